// Round 11
// baseline (145.797 us; speedup 1.0000x reference)
//
#include <hip/hip_runtime.h>
#include <hip/hip_bf16.h>

// Problem constants
#define Bb 2
#define Nn 4096
#define Cc 1024
#define Hh 16
#define Dd 64
#define Mm (Bb*Nn)      // 8192
#define W2 10
#define WINSZ 21        // 2*W2+1

typedef __attribute__((ext_vector_type(8))) short  bf16x8s;
typedef __attribute__((ext_vector_type(4))) float  f32x4;
typedef __attribute__((ext_vector_type(4))) unsigned short us4;

#define AS1 __attribute__((address_space(1)))
#define AS3 __attribute__((address_space(3)))

__device__ __forceinline__ unsigned short f2bf(float f) {
  unsigned int u = __float_as_uint(f);
  u += 0x7FFFu + ((u >> 16) & 1u);
  return (unsigned short)(u >> 16);
}
__device__ __forceinline__ float bflo(unsigned int u) { return __uint_as_float(u << 16); }
__device__ __forceinline__ float bfhi(unsigned int u) { return __uint_as_float(u & 0xFFFF0000u); }

__device__ __forceinline__ us4 cvt4(float4 v) {
  us4 o;
  o.x = f2bf(v.x); o.y = f2bf(v.y); o.z = f2bf(v.z); o.w = f2bf(v.w);
  return o;
}

// ---------------- fused fp32->bf16 converts + bias gather (one launch) ----------------
__global__ __launch_bounds__(256) void cvt_all(const float4* __restrict__ q,
                                               const float4* __restrict__ wq,
                                               const float4* __restrict__ wk,
                                               const float4* __restrict__ wv,
                                               const float4* __restrict__ wo,
                                               const float* __restrict__ bq,
                                               const float* __restrict__ bk,
                                               const float* __restrict__ bv,
                                               us4* __restrict__ qb4,
                                               us4* __restrict__ wqkv4,
                                               us4* __restrict__ wo4,
                                               float* __restrict__ bqkv) {
  const int NQ = 2097152, NW = 262144, TOT = NQ + 4 * NW;
  const int gid = blockIdx.x * 256 + threadIdx.x;
  const int stride = gridDim.x * 256;
  for (int i = gid; i < TOT; i += stride) {
    if (i < NQ) {
      qb4[i] = cvt4(q[i]);
    } else {
      int j = i - NQ;
      int r = j >> 18, k = j & (NW - 1);
      if (r == 0)      wqkv4[k]          = cvt4(wq[k]);
      else if (r == 1) wqkv4[NW + k]     = cvt4(wk[k]);
      else if (r == 2) wqkv4[2 * NW + k] = cvt4(wv[k]);
      else             wo4[k]            = cvt4(wo[k]);
    }
  }
  if (gid < 3072) {
    float v = (gid < 1024) ? bq[gid] : (gid < 2048) ? bk[gid - 1024] : bv[gid - 2048];
    bqkv[gid] = v;
  }
}

// ---------------- 256x256 8-phase pipelined bf16 NT GEMM (K=1024, m201-style) ----------------
// 8 waves (2M x 4N, per-wave 128x64 out). dbuf0 = even K-tiles, dbuf1 = odd.
// Per phase: {ds_read quadrant regs | stage half-tile(s)} ; barrier ; lgkmcnt(0) ;
// setprio(1) 16 MFMA setprio(0) ; [P4/P8: vmcnt(4)] ; barrier.
// Region ledger (all certified by an earlier lgkmcnt+closing-barrier):
//   d1.A (tile 2j+1) staged P1,P2(j)  — freed by P8(j-1); read P5-8(j)
//   d0.B (tile 2j+2) staged P2,P3(j)  — freed by P1(j) (B read once to regs); read P1(j+1)
//   d0.A (tile 2j+2) staged P5,P6(j)  — freed by P4(j); read P1-4(j+1)
//   d1.B (tile 2j+3) staged P6,P7(j)  — freed by P5(j); read P5(j+1)
// Tail stages clamp tile&15 (write never-read regions); iter0 d1.A restage is identical bytes.
template<bool OUT_BF16>
__global__ __launch_bounds__(512) void gemm8p(const unsigned short* __restrict__ A,
                                              const unsigned short* __restrict__ Bm,
                                              const float* __restrict__ bias,
                                              void* __restrict__ Cout,
                                              int N) {
  constexpr int K = 1024;
  __shared__ unsigned short lds[65536];   // 128 KB: [2 dbuf][Ah0|Ah1|Bh0|Bh1][128][64]

  const int tid = threadIdx.x, wid = tid >> 6, lane = tid & 63;
  const int wm = wid >> 2, wn = wid & 3;

  // bijective XCD swizzle, column-major tile walk
  const int nwg = gridDim.x, cpx = nwg >> 3, bid = blockIdx.x;
  const int swz = (bid & 7) * cpx + (bid >> 3);
  constexpr int NBM = Mm / 256;   // 32
  const int m0 = (swz % NBM) << 8, n0 = (swz / NBM) << 8;

  // staging source: thread t covers row (t>>3) of a 64-row group, chunk t&7;
  // pre-swizzled global chunk = (lane&7)^(lane>>3) (8-row-period involution)
  const int rbase = wid * 8 + (lane >> 3);
  const int cst = ((lane & 7) ^ (lane >> 3)) * 8;
  const unsigned short* aP0 = A  + (size_t)(m0 + rbase) * K + cst;
  const unsigned short* aP1 = aP0 + (size_t)128 * K;
  const unsigned short* bP0 = Bm + (size_t)(n0 + rbase) * K + cst;
  const unsigned short* bP1 = bP0 + (size_t)128 * K;

  // read bases (elems): A region = wm half; B region = (wn>>1) half, (wn&1) sub
  const int awb = wm * 8192 + (lane & 15) * 64;
  const int bwb = 16384 + (wn >> 1) * 8192 + (wn & 1) * 4096 + (lane & 15) * 64;
  const int chs0 = (((lane >> 4)) ^ (lane & 7)) * 8;
  const int chs1 = ((4 + (lane >> 4)) ^ (lane & 7)) * 8;

  f32x4 acc[8][4] = {};
  bf16x8s breg[4][2], areg[2][2];

#define GL(sp, off) __builtin_amdgcn_global_load_lds((AS1 const void*)(sp), (AS3 void*)(&lds[off]), 16, 0, 0)
#define STGA(d,h,kt) do { const unsigned short* _s = ((h) ? aP1 : aP0) + (size_t)(kt) * 64; \
    GL(_s,                   (d)*32768 + (h)*8192 +        wid*512); \
    GL(_s + (size_t)64 * K,  (d)*32768 + (h)*8192 + 4096 + wid*512); } while (0)
#define STGB(d,h,kt) do { const unsigned short* _s = ((h) ? bP1 : bP0) + (size_t)(kt) * 64; \
    GL(_s,                   (d)*32768 + 16384 + (h)*8192 +        wid*512); \
    GL(_s + (size_t)64 * K,  (d)*32768 + 16384 + (h)*8192 + 4096 + wid*512); } while (0)
#define LDB(d) do { _Pragma("unroll") for (int fn = 0; fn < 4; ++fn) { \
    breg[fn][0] = *(const bf16x8s*)(&lds[(d)*32768 + bwb + fn*1024 + chs0]); \
    breg[fn][1] = *(const bf16x8s*)(&lds[(d)*32768 + bwb + fn*1024 + chs1]); } } while (0)
#define LDA(d,q) do { _Pragma("unroll") for (int u = 0; u < 2; ++u) { \
    areg[u][0] = *(const bf16x8s*)(&lds[(d)*32768 + awb + ((q)*2+u)*1024 + chs0]); \
    areg[u][1] = *(const bf16x8s*)(&lds[(d)*32768 + awb + ((q)*2+u)*1024 + chs1]); } } while (0)
#define MF16(q) do { _Pragma("unroll") for (int u = 0; u < 2; ++u) _Pragma("unroll") for (int fn = 0; fn < 4; ++fn) { \
    acc[(q)*2+u][fn] = __builtin_amdgcn_mfma_f32_16x16x32_bf16(areg[u][0], breg[fn][0], acc[(q)*2+u][fn], 0, 0, 0); \
    acc[(q)*2+u][fn] = __builtin_amdgcn_mfma_f32_16x16x32_bf16(areg[u][1], breg[fn][1], acc[(q)*2+u][fn], 0, 0, 0); } } while (0)
#define SB __builtin_amdgcn_sched_barrier(0)
#define BAR __builtin_amdgcn_s_barrier()
#define LGKM0 asm volatile("s_waitcnt lgkmcnt(0)" ::: "memory")
#define PRIO1 __builtin_amdgcn_s_setprio(1)
#define PRIO0 __builtin_amdgcn_s_setprio(0)

  // prologue: stage tile 0 -> dbuf0 (first 8 loads), tile 1 -> dbuf1
  STGA(0,0,0); STGA(0,1,0); STGB(0,0,0); STGB(0,1,0);
  STGA(1,0,1); STGA(1,1,1); STGB(1,0,1); STGB(1,1,1);
  asm volatile("s_waitcnt vmcnt(8)" ::: "memory");   // tile 0 landed
  SB; BAR; SB;

#pragma unroll 1
  for (int j = 0; j < 8; ++j) {
    const int tA1 = 2*j + 1;          // <=15 always
    const int t0  = (2*j + 2) & 15;
    const int tB1 = (2*j + 3) & 15;
    // ---- K-tile 2j (dbuf0) ----
    LDB(0); LDA(0,0); STGA(1,0,tA1);          SB; BAR; LGKM0; SB;   // P1
    PRIO1; MF16(0); PRIO0; SB; BAR; SB;
    LDA(0,1); STGA(1,1,tA1); STGB(0,0,t0);    SB; BAR; LGKM0; SB;   // P2
    PRIO1; MF16(1); PRIO0; SB; BAR; SB;
    LDA(0,2); STGB(0,1,t0);                   SB; BAR; LGKM0; SB;   // P3
    PRIO1; MF16(2); PRIO0; SB; BAR; SB;
    LDA(0,3);                                 SB; BAR; LGKM0; SB;   // P4
    PRIO1; MF16(3); PRIO0; SB;
    asm volatile("s_waitcnt vmcnt(4)" ::: "memory"); SB; BAR; SB;   // d1 complete
    // ---- K-tile 2j+1 (dbuf1) ----
    LDB(1); LDA(1,0); STGA(0,0,t0);           SB; BAR; LGKM0; SB;   // P5
    PRIO1; MF16(0); PRIO0; SB; BAR; SB;
    LDA(1,1); STGA(0,1,t0); STGB(1,0,tB1);    SB; BAR; LGKM0; SB;   // P6
    PRIO1; MF16(1); PRIO0; SB; BAR; SB;
    LDA(1,2); STGB(1,1,tB1);                  SB; BAR; LGKM0; SB;   // P7
    PRIO1; MF16(2); PRIO0; SB; BAR; SB;
    LDA(1,3);                                 SB; BAR; LGKM0; SB;   // P8
    PRIO1; MF16(3); PRIO0; SB;
    asm volatile("s_waitcnt vmcnt(4)" ::: "memory"); SB; BAR; SB;   // d0 complete
  }
#undef GL
#undef STGA
#undef STGB
#undef LDB
#undef LDA
#undef MF16

  // epilogue: C/D layout col=lane&15, row=(lane>>4)*4+r
  const int r0 = m0 + wm * 128 + (lane >> 4) * 4;
  const int c0 = n0 + wn * 64 + (lane & 15);
#pragma unroll
  for (int fm = 0; fm < 8; ++fm) {
#pragma unroll
    for (int fn = 0; fn < 4; ++fn) {
      const int col = c0 + fn * 16;
      const float bv = bias[col];
#pragma unroll
      for (int r = 0; r < 4; ++r) {
        const int row = r0 + fm * 16 + r;
        const float v = acc[fm][fn][r] + bv;
        if (OUT_BF16)
          ((unsigned short*)Cout)[(size_t)row * N + col] = f2bf(v);
        else
          ((float*)Cout)[(size_t)row * N + col] = v;
      }
    }
  }
}

// ---------------- banded local attention: 2 threads per (b,h,n) row ----------------
#define TN 128
#define KVROWS (TN + 2 * W2)   // 148 staged rows

__global__ void attn_kernel(const unsigned short* __restrict__ QKV, // [Mm][3072]
                            unsigned short* __restrict__ AO,        // [Mm][1024]
                            float* __restrict__ attn_last) {        // [Bb*Hh*11]
  __shared__ uint4 Kl[KVROWS * 8];
  __shared__ uint4 Vl[KVROWS * 8];

  const int nt = Nn / TN;            // 32
  const int bid = blockIdx.x;
  const int tile = bid & (nt - 1);
  const int bh = bid / nt;
  const int h = bh & (Hh - 1), b = bh / Hh;
  const int n0 = tile * TN;
  const int tid = threadIdx.x;

  for (int idx = tid; idx < KVROWS * 8; idx += 256) {
    const int r = idx >> 3, c = idx & 7;
    const int pos = n0 - W2 + r;
    uint4 kv = make_uint4(0, 0, 0, 0), vv = make_uint4(0, 0, 0, 0);
    if (pos >= 0 && pos < Nn) {
      const uint4* row = (const uint4*)(QKV + (size_t)(b * Nn + pos) * 3072);
      kv = row[128 + h * 8 + c];
      vv = row[256 + h * 8 + c];
    }
    const int slot = c ^ (r & 7);
    Kl[r * 8 + slot] = kv;
    Vl[r * 8 + slot] = vv;
  }
  __syncthreads();

  const int row  = tid >> 1;
  const int half = tid & 1;
  const int n = n0 + row;
  const size_t m = (size_t)b * Nn + n;

  const uint4* qrow = (const uint4*)(QKV + m * 3072) + h * 8 + half * 4;
  const uint4 qd0 = qrow[0], qd1 = qrow[1], qd2 = qrow[2], qd3 = qrow[3];

  float p[WINSZ];
#pragma unroll
  for (int w = 0; w < WINSZ; ++w) p[w] = 0.f;

#pragma unroll
  for (int c = 0; c < 4; ++c) {
    const uint4 qv = (c == 0) ? qd0 : (c == 1) ? qd1 : (c == 2) ? qd2 : qd3;
    const float q0 = bflo(qv.x), q1 = bfhi(qv.x);
    const float q2 = bflo(qv.y), q3 = bfhi(qv.y);
    const float q4 = bflo(qv.z), q5 = bfhi(qv.z);
    const float q6 = bflo(qv.w), q7 = bfhi(qv.w);
#pragma unroll 7
    for (int w = 0; w < WINSZ; ++w) {
      const int r = row + w;
      const uint4 v = Kl[r * 8 + ((half * 4 + c) ^ (r & 7))];
      float a0 = q0 * bflo(v.x);
      float a1 = q1 * bfhi(v.x);
      a0 += q2 * bflo(v.y);
      a1 += q3 * bfhi(v.y);
      a0 += q4 * bflo(v.z);
      a1 += q5 * bfhi(v.z);
      a0 += q6 * bflo(v.w);
      a1 += q7 * bfhi(v.w);
      p[w] += a0 + a1;
    }
  }

#pragma unroll
  for (int w = 0; w < WINSZ; ++w) {
    float t = p[w];
    t += __shfl_xor(t, 1, 64);
    const int pos = n - W2 + w;
    p[w] = (pos < 0 || pos >= Nn) ? -1e30f : t * 0.125f;
  }
  float mx = p[0];
#pragma unroll
  for (int w = 1; w < WINSZ; ++w) mx = fmaxf(mx, p[w]);
  float sum = 0.f;
#pragma unroll
  for (int w = 0; w < WINSZ; ++w) { p[w] = __expf(p[w] - mx); sum += p[w]; }
  const float inv = 1.0f / sum;

  if (n == Nn - 1 && half == 0) {
#pragma unroll
    for (int w = 0; w <= W2; ++w)
      attn_last[(b * Hh + h) * (W2 + 1) + w] = p[w] * inv;
  }

  uint4* orow = (uint4*)(AO + m * Cc + h * Dd) + half * 4;
#pragma unroll
  for (int c = 0; c < 4; ++c) {
    float o0 = 0.f, o1 = 0.f, o2 = 0.f, o3 = 0.f;
    float o4 = 0.f, o5 = 0.f, o6 = 0.f, o7 = 0.f;
#pragma unroll 7
    for (int w = 0; w < WINSZ; ++w) {
      const int r = row + w;
      const uint4 v = Vl[r * 8 + ((half * 4 + c) ^ (r & 7))];
      const float pw = p[w];
      o0 += pw * bflo(v.x);
      o1 += pw * bfhi(v.x);
      o2 += pw * bflo(v.y);
      o3 += pw * bfhi(v.y);
      o4 += pw * bflo(v.z);
      o5 += pw * bfhi(v.z);
      o6 += pw * bflo(v.w);
      o7 += pw * bfhi(v.w);
    }
    unsigned int d0 = (unsigned int)f2bf(o0 * inv) | ((unsigned int)f2bf(o1 * inv) << 16);
    unsigned int d1 = (unsigned int)f2bf(o2 * inv) | ((unsigned int)f2bf(o3 * inv) << 16);
    unsigned int d2 = (unsigned int)f2bf(o4 * inv) | ((unsigned int)f2bf(o5 * inv) << 16);
    unsigned int d3 = (unsigned int)f2bf(o6 * inv) | ((unsigned int)f2bf(o7 * inv) << 16);
    orow[c] = make_uint4(d0, d1, d2, d3);
  }
}

// ---------------- launch ----------------
extern "C" void kernel_launch(void* const* d_in, const int* in_sizes, int n_in,
                              void* d_out, int out_size, void* d_ws, size_t ws_size,
                              hipStream_t stream) {
  const float* q    = (const float*)d_in[0];
  const float* Wq_w = (const float*)d_in[1];
  const float* Wq_b = (const float*)d_in[2];
  const float* Wk_w = (const float*)d_in[3];
  const float* Wk_b = (const float*)d_in[4];
  const float* Wv_w = (const float*)d_in[5];
  const float* Wv_b = (const float*)d_in[6];
  const float* Wo_w = (const float*)d_in[7];
  const float* Wo_b = (const float*)d_in[8];
  float* out = (float*)d_out;                       // [Mm*Cc] + [Bb*Hh*11]
  float* attn_last = out + (size_t)Mm * Cc;

  // workspace carve (bytes)
  char* ws = (char*)d_ws;
  unsigned short* qb   = (unsigned short*)(ws);                       // 16 MB
  unsigned short* Wqkv = (unsigned short*)(ws + 16777216);            // 6 MB
  unsigned short* Wo16 = (unsigned short*)(ws + 16777216 + 6291456);  // 2 MB
  float*          bqkv = (float*)(ws + 25165824);                     // 3072 f32
  unsigned short* QKV  = (unsigned short*)(ws + 25182208);            // 48 MB
  unsigned short* AO   = (unsigned short*)(ws + 75513856);            // 16 MB

  // 1) fused converts (q, Wq, Wk, Wv, Wo) + bias gather — one launch
  cvt_all<<<2048, 256, 0, stream>>>((const float4*)q,
                                    (const float4*)Wq_w, (const float4*)Wk_w,
                                    (const float4*)Wv_w, (const float4*)Wo_w,
                                    Wq_b, Wk_b, Wv_b,
                                    (us4*)qb, (us4*)Wqkv, (us4*)Wo16, bqkv);

  // 2) fused QKV projection: [8192,1024] x [3072,1024]^T -> bf16 [8192,3072]
  {
    dim3 grid((Mm / 256) * (3072 / 256));   // 384, %8==0
    gemm8p<true><<<grid, 512, 0, stream>>>(qb, Wqkv, bqkv, (void*)QKV, 3072);
  }

  // 3) windowed attention -> bf16 [8192,1024] + attn_last tail of d_out
  {
    dim3 grid(Bb * Hh * (Nn / TN));
    attn_kernel<<<grid, 256, 0, stream>>>(QKV, AO, attn_last);
  }

  // 4) output projection: [8192,1024] x [1024,1024]^T -> fp32 d_out
  {
    dim3 grid((Mm / 256) * (Cc / 256));     // 128, %8==0
    gemm8p<false><<<grid, 512, 0, stream>>>(AO, Wo16, Wo_b, (void*)out, Cc);
  }
}